// Round 7
// baseline (291.123 us; speedup 1.0000x reference)
//
#include <hip/hip_runtime.h>
#include <hip/hip_bf16.h>
#include <math.h>

#define T_N 32768
#define D_N 256
#define HID 32
#define LOG2E 1.44269504f
#define LN2   0.69314718f

typedef short  s16x8  __attribute__((ext_vector_type(8)));   // MFMA A/B frag
typedef float  f32x16 __attribute__((ext_vector_type(16)));  // MFMA C/D frag
typedef float  f32x4  __attribute__((ext_vector_type(4)));
typedef float  f32x2  __attribute__((ext_vector_type(2)));   // v_pk_*_f32 carrier

union FragU { s16x8 v; unsigned u[4]; unsigned short s[8]; };

// ---- conversions ----
static __device__ __forceinline__ unsigned short w2b(float f) {
    union { __hip_bfloat16 h; unsigned short s; } u;
    u.h = __float2bfloat16(f); return u.s;
}
// hot-path pack, TRUNCATING: single v_perm (proven r6, absmax unchanged).
// NOTE: v_cvt_pk_bf16_f32 inline asm = garbage on this toolchain (r1-2).
static __device__ __forceinline__ unsigned pktr(float a, float b) {
#if __has_builtin(__builtin_amdgcn_perm)
    return __builtin_amdgcn_perm(__float_as_uint(b), __float_as_uint(a),
                                 0x07060302u);   // {a.hi16 | b.hi16<<16}
#else
    return (__float_as_uint(a) >> 16) | (__float_as_uint(b) & 0xFFFF0000u);
#endif
}
// RHU pack (3 ops) kept for the layer-1 feature frag only.
static __device__ __forceinline__ unsigned pkrh(float a, float b) {
    const unsigned ua = __float_as_uint(a) + 0x8000u;
    const unsigned ub = __float_as_uint(b) + 0x8000u;
#if __has_builtin(__builtin_amdgcn_perm)
    return __builtin_amdgcn_perm(ub, ua, 0x07060302u);
#else
    return (ua >> 16) | (ub & 0xFFFF0000u);
#endif
}
// cross-half exchange (in-place), lane[i] <-> lane[i+32]. PROVEN round 3.
static __device__ __forceinline__ void pl32(unsigned &a, unsigned &b) {
    asm("v_permlane32_swap_b32 %0, %1" : "+v"(a), "+v"(b));
}
static __device__ __forceinline__ float exp2neg(float t) {   // 2^(-t)
#if __has_builtin(__builtin_amdgcn_exp2f)
    return __builtin_amdgcn_exp2f(-t);
#else
    return __expf(-t * LN2);
#endif
}

// ---- LUT scaled-silu (round 7) ----
// r6 audit: v_exp/v_rcp ~16cy/wave64 -> trans = 76% of VALU busy. Replace
// per-value {exp + batched-rcp chain} (~25.5 cy) with PWL table lookup:
// f(t) = t/(1+2^-t) = log2e*silu(preact), 256 affine segments over
// [-16,16] (h=0.125, interp err <= h^2/8*max|f''| ~ 5e-4 < bf16 pack
// noise). 5 full-rate VALU + ds_read_b64 (idle LDS pipe; r3 proved LDS
// latency fully hidden here) + 1 fma = ~12 cy/value.
// tc = max(t,-16) bounds low-side extrapolation (~3e-4); top segment has
// slope ~1 so t>16 is exact; index fmin-clamped to 255.
static __device__ __forceinline__ float lutsilu(float t, const float2 *lut) {
    const float tc = fmaxf(t, -16.0f);
    float fi = fmaf(tc, 8.0f, 128.0f);     // segment coordinate
    fi = fminf(fi, 255.0f);
    const float2 ab = lut[(unsigned)fi];   // cvt + shl + ds_read_b64
    return fmaf(ab.x, tc, ab.y);           // a*t + b
}

// activation + pack + half-wave transpose for one 32x32 layer output
static __device__ __forceinline__ void actsec(const f32x16 &h, const float2 *lut,
                                              FragU &bh0, FragU &bh1) {
    unsigned w[8];
    #pragma unroll
    for (int g = 0; g < 8; ++g)
        w[g] = pktr(lutsilu(h[2*g], lut), lutsilu(h[2*g+1], lut));
    // pairs (w0..w7) = old (wx0,wy0,wx1,wy1,wx2,wy2,wx3,wy3)
    pl32(w[0], w[2]); pl32(w[1], w[3]); pl32(w[4], w[6]); pl32(w[5], w[7]);
    bh0.u[0] = w[0]; bh0.u[1] = w[1]; bh0.u[2] = w[2]; bh0.u[3] = w[3];
    bh1.u[0] = w[4]; bh1.u[1] = w[5]; bh1.u[2] = w[6]; bh1.u[3] = w[7];
}
// head: act + packed dot with W4 (per-lane partial, pre-shfl)
static __device__ __forceinline__ float headsec(const f32x16 &h, const float2 *lut,
                                                const f32x2 *w4p) {
    f32x2 pacc = {0.0f, 0.0f};
    #pragma unroll
    for (int g = 0; g < 8; ++g) {
        f32x2 o; o[0] = lutsilu(h[2*g], lut); o[1] = lutsilu(h[2*g+1], lut);
        pacc += o * w4p[g];               // v_pk_fma_f32
    }
    return pacc[0] + pacc[1];
}

// TWO observations per wave (proven r5); issue-saturated regime (r5-r6:
// VALUBusy+MfmaUtil ~98%), so r7 cuts the dominant VALU consumer (trans).
// Layouts (m74/m101): A[m=lane&31][k=(lane>>5)*8+j], B[k][n=lane&31],
//   C/D: col=lane&31, row=(reg&3)+8*(reg>>2)+4*(lane>>5)
// Inter-layer transpose: 4x v_permlane32_swap_b32 per layer (proven r3).
// exp2-domain scaling: W1,b1..b3 *log2e, W4 *ln2 (scales telescope);
// LUT returns values already in the log2e domain.
__global__ __launch_bounds__(256, 3) void dose_encoder_kernel(
    const float* __restrict__ t_abs,
    const float* __restrict__ dose_t,
    const float* __restrict__ amts,
    const float* __restrict__ ss,
    const float* __restrict__ ii,
    const float* __restrict__ span_p,
    const float* __restrict__ logsig_p,
    const float* __restrict__ W1, const float* __restrict__ b1,
    const float* __restrict__ W2, const float* __restrict__ b2,
    const float* __restrict__ W3, const float* __restrict__ b3,
    const float* __restrict__ W4, const float* __restrict__ b4,
    float* __restrict__ out)
{
    // pd: {dose_f32, bits(pk(amt,ss)), bits(pk(ii,0)), unused}
    __shared__ f32x4 pd[D_N];
    __shared__ float2 lut[256];           // PWL silu table (2 KB)

    const int tid  = threadIdx.x;
    const int wv   = tid >> 6;
    const int lane = tid & 63;
    const int n    = lane & 31;       // dose column
    const int hh   = lane >> 5;       // k-half
    const int t0   = blockIdx.x * 8 + wv * 2;   // obs pair {t0, t0+1}

    const float span   = span_p[0];
    const float inv_se = 1.0f / (span + 1e-6f);
    const float inv_sp = 1.0f / span;
    const float sigma  = __expf(logsig_p[0]);
    const float gk     = sqrtf(0.5f * LOG2E) / sigma;   // wgt = 2^(-(dt*gk)^2)

    { f32x4 e;
      e[0] = dose_t[tid];
      e[1] = __uint_as_float(((unsigned)w2b(log1pf(amts[tid]))) |
                             ((unsigned)w2b(ss[tid] * inv_se) << 16));
      e[2] = __uint_as_float((unsigned)w2b(ii[tid] * inv_se));
      e[3] = 0.0f;
      pd[tid] = e; }
    {   // PWL table: entry k covers t in [-16 + k/8, -16 + (k+1)/8)
        const float t0k = -16.0f + (float)tid * 0.125f;
        const float t1k = t0k + 0.125f;
        const float f0  = t0k / (1.0f + exp2neg(t0k));
        const float f1  = t1k / (1.0f + exp2neg(t1k));
        const float a   = (f1 - f0) * 8.0f;
        lut[tid] = make_float2(a, fmaf(-a, t0k, f0));
    }
    __syncthreads();

    const float tvA = t_abs[t0];
    const float tvB = t_abs[t0 + 1];
    const float lastd = dose_t[D_N - 1];
    const float dtlA = (tvA - lastd) * inv_sp;  // doses sorted, all < t_abs
    const float dtlB = (tvB - lastd) * inv_sp;

    // ---- one-time weight fragments (wave-uniform addresses -> s_loads) ----
    // k-row order for layer 1: {dt, dt_last, amt, ss, ii} = W1 rows {0,2,1,3,4}
    FragU a1;
    {
        const int kmap[5] = {0, 2, 1, 3, 4};
        #pragma unroll
        for (int j = 0; j < 8; ++j) {
            const int k = hh * 8 + j;
            a1.s[j] = (k < 5) ? w2b(LOG2E * W1[kmap[k] * HID + n]) : (unsigned short)0;
        }
    }
    FragU a2[2], a3[2];
    #pragma unroll
    for (int mf = 0; mf < 2; ++mf)
        #pragma unroll
        for (int j = 0; j < 8; ++j) {
            const int k = mf * 16 + hh * 8 + j;
            a2[mf].s[j] = w2b(W2[k * HID + n]);
            a3[mf].s[j] = w2b(W3[k * HID + n]);
        }
    f32x16 c1, c2, c3; f32x2 w4p[8];
    #pragma unroll
    for (int r = 0; r < 16; ++r) {
        const int row = (r & 3) + 8 * (r >> 2) + 4 * hh;
        c1[r] = LOG2E * b1[row];
        c2[r] = LOG2E * b2[row];
        c3[r] = LOG2E * b3[row];
        w4p[r >> 1][r & 1] = LN2 * W4[row];
    }
    const float b4s = b4[0];

    FragU bfA, bfB;
    bfA.u[3] = bfB.u[3] = 0u;        // hoisted zero rows

    float accA = 0.0f, accB = 0.0f;
    #pragma unroll 1
    for (int c = 0; c < 8; ++c) {
        const f32x4 p    = pd[c * 32 + n];
        const float dtvA = (tvA - p[0]) * inv_sp;
        const float dtvB = (tvB - p[0]) * inv_sp;

        // feature B-frags: rows k=0..4 in hh=0 lanes; A rows k>=5 are zero.
        // Dose-side features (u[1],u[2]) shared between the two obs.
        bfA.u[0] = pkrh(dtvA, dtlA);
        bfB.u[0] = pkrh(dtvB, dtlB);
        bfA.u[1] = bfB.u[1] = __float_as_uint(p[1]);   // amt, ss (prepacked)
        bfA.u[2] = bfB.u[2] = __float_as_uint(p[2]);   // ii, 0   (prepacked)

        // ---- layer 1 (two independent spines) ----
        f32x16 hA = __builtin_amdgcn_mfma_f32_32x32x16_bf16(a1.v, bfA.v, c1, 0, 0, 0);
        f32x16 hB = __builtin_amdgcn_mfma_f32_32x32x16_bf16(a1.v, bfB.v, c1, 0, 0, 0);

        FragU bhA0, bhA1, bhB0, bhB1;
        actsec(hA, lut, bhA0, bhA1);
        actsec(hB, lut, bhB0, bhB1);

        // ---- layer 2 ----
        hA = __builtin_amdgcn_mfma_f32_32x32x16_bf16(a2[0].v, bhA0.v, c2, 0, 0, 0);
        hA = __builtin_amdgcn_mfma_f32_32x32x16_bf16(a2[1].v, bhA1.v, hA, 0, 0, 0);
        hB = __builtin_amdgcn_mfma_f32_32x32x16_bf16(a2[0].v, bhB0.v, c2, 0, 0, 0);
        hB = __builtin_amdgcn_mfma_f32_32x32x16_bf16(a2[1].v, bhB1.v, hB, 0, 0, 0);

        actsec(hA, lut, bhA0, bhA1);
        actsec(hB, lut, bhB0, bhB1);

        // ---- layer 3 + head ----
        hA = __builtin_amdgcn_mfma_f32_32x32x16_bf16(a3[0].v, bhA0.v, c3, 0, 0, 0);
        hA = __builtin_amdgcn_mfma_f32_32x32x16_bf16(a3[1].v, bhA1.v, hA, 0, 0, 0);
        hB = __builtin_amdgcn_mfma_f32_32x32x16_bf16(a3[0].v, bhB0.v, c3, 0, 0, 0);
        hB = __builtin_amdgcn_mfma_f32_32x32x16_bf16(a3[1].v, bhB1.v, hB, 0, 0, 0);

        float partA = headsec(hA, lut, w4p);
        float partB = headsec(hB, lut, w4p);
        partA += __shfl_xor(partA, 32, 64);       // sum the two k-halves
        partB += __shfl_xor(partB, 32, 64);
        const float scoreA = partA + b4s;
        const float scoreB = partB + b4s;

        const float qA = dtvA * gk;
        const float qB = dtvB * gk;
        float wgtA = exp2neg(qA * qA);
        float wgtB = exp2neg(qB * qB);
        wgtA = (dtvA >= 0.0f) ? wgtA : 0.0f;
        wgtB = (dtvB >= 0.0f) ? wgtB : 0.0f;
        accA = fmaf(scoreA, wgtA, accA);
        accB = fmaf(scoreB, wgtB, accB);
    }

    // reduce over the 32 dose-columns (halves already folded via shfl 32)
    #pragma unroll
    for (int off = 1; off < 32; off <<= 1) {
        accA += __shfl_xor(accA, off, 64);
        accB += __shfl_xor(accB, off, 64);
    }
    if (lane == 0) { out[t0] = accA; out[t0 + 1] = accB; }
}

extern "C" void kernel_launch(void* const* d_in, const int* in_sizes, int n_in,
                              void* d_out, int out_size, void* d_ws, size_t ws_size,
                              hipStream_t stream) {
    const float* t_abs  = (const float*)d_in[0];
    const float* dose_t = (const float*)d_in[1];
    const float* amts   = (const float*)d_in[2];
    const float* ss     = (const float*)d_in[3];
    const float* ii     = (const float*)d_in[4];
    const float* span_p = (const float*)d_in[5];
    const float* logsig = (const float*)d_in[6];
    const float* W1 = (const float*)d_in[7];
    const float* b1 = (const float*)d_in[8];
    const float* W2 = (const float*)d_in[9];
    const float* b2 = (const float*)d_in[10];
    const float* W3 = (const float*)d_in[11];
    const float* b3 = (const float*)d_in[12];
    const float* W4 = (const float*)d_in[13];
    const float* b4 = (const float*)d_in[14];
    float* out = (float*)d_out;

    dose_encoder_kernel<<<dim3(T_N / 8), dim3(256), 0, stream>>>(
        t_abs, dose_t, amts, ss, ii, span_p, logsig,
        W1, b1, W2, b2, W3, b3, W4, b4, out);
}

// Round 12
// 222.406 us; speedup vs baseline: 1.3090x; 1.3090x over previous
//
#include <hip/hip_runtime.h>
#include <hip/hip_bf16.h>
#include <math.h>

#define T_N 32768
#define D_N 256
#define HID 32
#define LOG2E 1.44269504f
#define LN2   0.69314718f

typedef short  s16x8  __attribute__((ext_vector_type(8)));   // MFMA A/B frag
typedef float  f32x16 __attribute__((ext_vector_type(16)));  // MFMA C/D frag
typedef float  f32x4  __attribute__((ext_vector_type(4)));
typedef float  f32x2  __attribute__((ext_vector_type(2)));   // v_pk_*_f32 carrier

union FragU { s16x8 v; unsigned u[4]; unsigned short s[8]; };

// ---- conversions ----
static __device__ __forceinline__ unsigned short w2b(float f) {
    union { __hip_bfloat16 h; unsigned short s; } u;
    u.h = __float2bfloat16(f); return u.s;
}
// hot-path pack, TRUNCATING: single v_perm (proven r6, absmax unchanged).
// NOTE: v_cvt_pk_bf16_f32 inline asm = garbage on this toolchain (r1-2).
static __device__ __forceinline__ unsigned pktr(float a, float b) {
#if __has_builtin(__builtin_amdgcn_perm)
    return __builtin_amdgcn_perm(__float_as_uint(b), __float_as_uint(a),
                                 0x07060302u);   // {a.hi16 | b.hi16<<16}
#else
    return (__float_as_uint(a) >> 16) | (__float_as_uint(b) & 0xFFFF0000u);
#endif
}
static __device__ __forceinline__ unsigned pk2(f32x2 v) { return pktr(v[0], v[1]); }
// RHU pack (3 ops, proven) for the layer-1 feature frag only.
static __device__ __forceinline__ unsigned pkrh(float a, float b) {
    const unsigned ua = __float_as_uint(a) + 0x8000u;
    const unsigned ub = __float_as_uint(b) + 0x8000u;
#if __has_builtin(__builtin_amdgcn_perm)
    return __builtin_amdgcn_perm(ub, ua, 0x07060302u);
#else
    return (ua >> 16) | (ub & 0xFFFF0000u);
#endif
}
// cross-half exchange (in-place), lane[i] <-> lane[i+32]. PROVEN round 3.
static __device__ __forceinline__ void pl32(unsigned &a, unsigned &b) {
    asm("v_permlane32_swap_b32 %0, %1" : "+v"(a), "+v"(b));
}
static __device__ __forceinline__ float exp2neg(float t) {   // 2^(-t)
#if __has_builtin(__builtin_amdgcn_exp2f)
    return __builtin_amdgcn_exp2f(-t);
#else
    return __expf(-t * LN2);
#endif
}
// batched-reciprocal quad scaled-silu, PAIR-NATIVE (proven r6): operands
// are f32x2 views aliased onto the MFMA output's aligned register pairs.
// 4 values share one v_rcp_f32 (proven r4). o = t/(1+2^-t).
// Session floor note: 61 silu evals/obs-chunk x ~16cy trans = ~2/3 of the
// issue budget; exact-exp silu is the structural floor. LUT silu (r7) and
// tau-grid amortization (r8-r11) both falsified -- do not revisit blind.
static __device__ __forceinline__ void act4p(const f32x2 t01, const f32x2 t23,
                                             f32x2 &o01, f32x2 &o23) {
    f32x2 e01; e01[0] = exp2neg(t01[0]); e01[1] = exp2neg(t01[1]);
    f32x2 e23; e23[0] = exp2neg(t23[0]); e23[1] = exp2neg(t23[1]);
    const f32x2 d01 = e01 + 1.0f;                 // v_pk_add_f32
    const f32x2 d23 = e23 + 1.0f;
    const f32x2 pp  = d01 * d23;                  // (d0d2, d1d3)
    const float r   = __builtin_amdgcn_rcpf(pp[0] * pp[1]);
    f32x2 rs; rs[0] = r * pp[1]; rs[1] = r * pp[0];   // (1/d0d2, 1/d1d3)
    o01 = t01 * (rs * d23);                       // t * (1/d)
    o23 = t23 * (rs * d01);
}

// activation + pack + half-wave transpose for one 32x32 layer output
static __device__ __forceinline__ void actsec(const f32x16 &h, FragU &bh0, FragU &bh1) {
    const f32x2 *hp = (const f32x2 *)&h;          // aligned pair views
    f32x2 s0, s1, s2, s3, s4, s5, s6, s7;
    act4p(hp[0], hp[1], s0, s1);
    act4p(hp[2], hp[3], s2, s3);
    act4p(hp[4], hp[5], s4, s5);
    act4p(hp[6], hp[7], s6, s7);
    unsigned wx0 = pk2(s0), wy0 = pk2(s1);   // G0: rows 4hh+{0,1},{2,3}
    unsigned wx1 = pk2(s2), wy1 = pk2(s3);   // G1: rows 8+4hh+...
    unsigned wx2 = pk2(s4), wy2 = pk2(s5);   // G2: rows 16+4hh+...
    unsigned wx3 = pk2(s6), wy3 = pk2(s7);   // G3: rows 24+4hh+...
    pl32(wx0, wx1); pl32(wy0, wy1); pl32(wx2, wx3); pl32(wy2, wy3);
    bh0.u[0] = wx0; bh0.u[1] = wy0; bh0.u[2] = wx1; bh0.u[3] = wy1;
    bh1.u[0] = wx2; bh1.u[1] = wy2; bh1.u[2] = wx3; bh1.u[3] = wy3;
}
// head: act + packed dot with W4 (per-lane partial, pre-shfl)
static __device__ __forceinline__ float headsec(const f32x16 &h, const f32x2 *w4p) {
    const f32x2 *hp = (const f32x2 *)&h;
    f32x2 pacc = {0.0f, 0.0f};
    #pragma unroll
    for (int g = 0; g < 4; ++g) {
        f32x2 oa, ob;
        act4p(hp[2*g], hp[2*g+1], oa, ob);
        pacc += oa * w4p[2*g];            // v_pk_fma_f32
        pacc += ob * w4p[2*g + 1];
    }
    return pacc[0] + pacc[1];
}

// TWO observations per wave (proven r5: filled the issue slots; VALUBusy+
// MfmaUtil ~98% -> issue-saturated).
// Layouts (m74/m101): A[m=lane&31][k=(lane>>5)*8+j], B[k][n=lane&31],
//   C/D: col=lane&31, row=(reg&3)+8*(reg>>2)+4*(lane>>5)
// Inter-layer transpose: 4x v_permlane32_swap_b32 per layer (proven r3).
// exp2-domain scaling: W1,b1..b3 *log2e, W4 *ln2 (scales telescope).
__global__ __launch_bounds__(256, 3) void dose_encoder_kernel(
    const float* __restrict__ t_abs,
    const float* __restrict__ dose_t,
    const float* __restrict__ amts,
    const float* __restrict__ ss,
    const float* __restrict__ ii,
    const float* __restrict__ span_p,
    const float* __restrict__ logsig_p,
    const float* __restrict__ W1, const float* __restrict__ b1,
    const float* __restrict__ W2, const float* __restrict__ b2,
    const float* __restrict__ W3, const float* __restrict__ b3,
    const float* __restrict__ W4, const float* __restrict__ b4,
    float* __restrict__ out)
{
    // pd: {dose_f32, bits(pk(amt,ss)), bits(pk(ii,0)), unused}
    __shared__ f32x4 pd[D_N];

    const int tid  = threadIdx.x;
    const int wv   = tid >> 6;
    const int lane = tid & 63;
    const int n    = lane & 31;       // dose column
    const int hh   = lane >> 5;       // k-half
    const int t0   = blockIdx.x * 8 + wv * 2;   // obs pair {t0, t0+1}

    const float span   = span_p[0];
    const float inv_se = 1.0f / (span + 1e-6f);
    const float inv_sp = 1.0f / span;
    const float sigma  = __expf(logsig_p[0]);
    const float gk     = sqrtf(0.5f * LOG2E) / sigma;   // wgt = 2^(-(dt*gk)^2)

    { f32x4 e;
      e[0] = dose_t[tid];
      e[1] = __uint_as_float(((unsigned)w2b(log1pf(amts[tid]))) |
                             ((unsigned)w2b(ss[tid] * inv_se) << 16));
      e[2] = __uint_as_float((unsigned)w2b(ii[tid] * inv_se));
      e[3] = 0.0f;
      pd[tid] = e; }
    __syncthreads();

    const float tvA = t_abs[t0];
    const float tvB = t_abs[t0 + 1];
    const float lastd = dose_t[D_N - 1];
    const float dtlA = (tvA - lastd) * inv_sp;  // doses sorted, all < t_abs
    const float dtlB = (tvB - lastd) * inv_sp;

    // ---- one-time weight fragments (wave-uniform addresses -> s_loads) ----
    // k-row order for layer 1: {dt, dt_last, amt, ss, ii} = W1 rows {0,2,1,3,4}
    FragU a1;
    {
        const int kmap[5] = {0, 2, 1, 3, 4};
        #pragma unroll
        for (int j = 0; j < 8; ++j) {
            const int k = hh * 8 + j;
            a1.s[j] = (k < 5) ? w2b(LOG2E * W1[kmap[k] * HID + n]) : (unsigned short)0;
        }
    }
    FragU a2[2], a3[2];
    #pragma unroll
    for (int mf = 0; mf < 2; ++mf)
        #pragma unroll
        for (int j = 0; j < 8; ++j) {
            const int k = mf * 16 + hh * 8 + j;
            a2[mf].s[j] = w2b(W2[k * HID + n]);
            a3[mf].s[j] = w2b(W3[k * HID + n]);
        }
    f32x16 c1, c2, c3; f32x2 w4p[8];
    #pragma unroll
    for (int r = 0; r < 16; ++r) {
        const int row = (r & 3) + 8 * (r >> 2) + 4 * hh;
        c1[r] = LOG2E * b1[row];
        c2[r] = LOG2E * b2[row];
        c3[r] = LOG2E * b3[row];
        w4p[r >> 1][r & 1] = LN2 * W4[row];
    }
    const float b4s = b4[0];

    FragU bfA, bfB;
    bfA.u[3] = bfB.u[3] = 0u;        // hoisted zero rows

    float accA = 0.0f, accB = 0.0f;
    #pragma unroll 1
    for (int c = 0; c < 8; ++c) {
        const f32x4 p    = pd[c * 32 + n];
        const float dtvA = (tvA - p[0]) * inv_sp;
        const float dtvB = (tvB - p[0]) * inv_sp;

        // feature B-frags: rows k=0..4 in hh=0 lanes; A rows k>=5 are zero.
        // Dose-side features (u[1],u[2]) shared between the two obs.
        bfA.u[0] = pkrh(dtvA, dtlA);
        bfB.u[0] = pkrh(dtvB, dtlB);
        bfA.u[1] = bfB.u[1] = __float_as_uint(p[1]);   // amt, ss (prepacked)
        bfA.u[2] = bfB.u[2] = __float_as_uint(p[2]);   // ii, 0   (prepacked)

        // ---- layer 1 (two independent spines) ----
        f32x16 hA = __builtin_amdgcn_mfma_f32_32x32x16_bf16(a1.v, bfA.v, c1, 0, 0, 0);
        f32x16 hB = __builtin_amdgcn_mfma_f32_32x32x16_bf16(a1.v, bfB.v, c1, 0, 0, 0);

        FragU bhA0, bhA1, bhB0, bhB1;
        actsec(hA, bhA0, bhA1);
        actsec(hB, bhB0, bhB1);

        // ---- layer 2 ----
        hA = __builtin_amdgcn_mfma_f32_32x32x16_bf16(a2[0].v, bhA0.v, c2, 0, 0, 0);
        hA = __builtin_amdgcn_mfma_f32_32x32x16_bf16(a2[1].v, bhA1.v, hA, 0, 0, 0);
        hB = __builtin_amdgcn_mfma_f32_32x32x16_bf16(a2[0].v, bhB0.v, c2, 0, 0, 0);
        hB = __builtin_amdgcn_mfma_f32_32x32x16_bf16(a2[1].v, bhB1.v, hB, 0, 0, 0);

        actsec(hA, bhA0, bhA1);
        actsec(hB, bhB0, bhB1);

        // ---- layer 3 + head ----
        hA = __builtin_amdgcn_mfma_f32_32x32x16_bf16(a3[0].v, bhA0.v, c3, 0, 0, 0);
        hA = __builtin_amdgcn_mfma_f32_32x32x16_bf16(a3[1].v, bhA1.v, hA, 0, 0, 0);
        hB = __builtin_amdgcn_mfma_f32_32x32x16_bf16(a3[0].v, bhB0.v, c3, 0, 0, 0);
        hB = __builtin_amdgcn_mfma_f32_32x32x16_bf16(a3[1].v, bhB1.v, hB, 0, 0, 0);

        float partA = headsec(hA, w4p);
        float partB = headsec(hB, w4p);
        partA += __shfl_xor(partA, 32, 64);       // sum the two k-halves
        partB += __shfl_xor(partB, 32, 64);
        const float scoreA = partA + b4s;
        const float scoreB = partB + b4s;

        const float qA = dtvA * gk;
        const float qB = dtvB * gk;
        float wgtA = exp2neg(qA * qA);
        float wgtB = exp2neg(qB * qB);
        wgtA = (dtvA >= 0.0f) ? wgtA : 0.0f;
        wgtB = (dtvB >= 0.0f) ? wgtB : 0.0f;
        accA = fmaf(scoreA, wgtA, accA);
        accB = fmaf(scoreB, wgtB, accB);
    }

    // reduce over the 32 dose-columns (halves already folded via shfl 32)
    #pragma unroll
    for (int off = 1; off < 32; off <<= 1) {
        accA += __shfl_xor(accA, off, 64);
        accB += __shfl_xor(accB, off, 64);
    }
    if (lane == 0) { out[t0] = accA; out[t0 + 1] = accB; }
}

extern "C" void kernel_launch(void* const* d_in, const int* in_sizes, int n_in,
                              void* d_out, int out_size, void* d_ws, size_t ws_size,
                              hipStream_t stream) {
    const float* t_abs  = (const float*)d_in[0];
    const float* dose_t = (const float*)d_in[1];
    const float* amts   = (const float*)d_in[2];
    const float* ss     = (const float*)d_in[3];
    const float* ii     = (const float*)d_in[4];
    const float* span_p = (const float*)d_in[5];
    const float* logsig = (const float*)d_in[6];
    const float* W1 = (const float*)d_in[7];
    const float* b1 = (const float*)d_in[8];
    const float* W2 = (const float*)d_in[9];
    const float* b2 = (const float*)d_in[10];
    const float* W3 = (const float*)d_in[11];
    const float* b3 = (const float*)d_in[12];
    const float* W4 = (const float*)d_in[13];
    const float* b4 = (const float*)d_in[14];
    float* out = (float*)d_out;

    dose_encoder_kernel<<<dim3(T_N / 8), dim3(256), 0, stream>>>(
        t_abs, dose_t, amts, ss, ii, span_p, logsig,
        W1, b1, W2, b2, W3, b3, W4, b4, out);
}